// Round 5
// baseline (130.965 us; speedup 1.0000x reference)
//
#include <hip/hip_runtime.h>
#include <math.h>

#define NTOK 100
#define EDIM 5
#define NH   4
#define NL   3
#define DD   64
#define BLK  128

// single-instruction transcendentals (1-ulp class; tolerance is 2^-7)
__device__ __forceinline__ float fexp2(float x){ float r; asm("v_exp_f32 %0, %1" : "=v"(r) : "v"(x)); return r; }
__device__ __forceinline__ float frcp (float x){ float r; asm("v_rcp_f32 %0, %1" : "=v"(r) : "v"(x)); return r; }
__device__ __forceinline__ float frsq (float x){ float r; asm("v_rsq_f32 %0, %1" : "=v"(r) : "v"(x)); return r; }
// wave-uniform register broadcast (lane index provably uniform via readfirstlane(nm))
#define RL(v, l) __int_as_float(__builtin_amdgcn_readlane(__float_as_int(v), (l)))

// ---------------------------------------------------------------------------
// Kernel 1: fold per-head projections into 5x5 matrices.
//   M[l][h] = (1/8)*log2(e) * Wq^T Wk    (softmax uses native v_exp_f32)
//   P[l][h] = Wv^T Wo_h^T
// ws layout: float [2][NL][NH][EDIM][8]
// ---------------------------------------------------------------------------
__global__ void precompute_mp(const float* __restrict__ Wq,
                              const float* __restrict__ Wk,
                              const float* __restrict__ Wv,
                              const float* __restrict__ Wo,
                              float* __restrict__ mp) {
  const int blk = blockIdx.x;            // 24 = which(2) * l(3) * h(4)
  const int which = blk / 12;
  const int rem = blk % 12;
  const int l = rem / 4, h = rem % 4;
  const int t = threadIdx.x;             // 64 threads

  __shared__ float A[320];               // [d*5+e]
  __shared__ float Bsh[320];             // which0: [d*5+f] ; which1: [f*64+d]

  const float* wa = (which ? Wv : Wq) + (l*NH + h)*DD*EDIM;
  for (int r = t; r < 320; r += 64) A[r] = wa[r];
  if (which == 0) {
    const float* wk = Wk + (l*NH + h)*DD*EDIM;
    for (int r = t; r < 320; r += 64) Bsh[r] = wk[r];
  } else {
    for (int r = t; r < 320; r += 64) {
      int f = r >> 6, d = r & 63;
      Bsh[r] = Wo[(l*EDIM + f)*(NH*DD) + h*DD + d];
    }
  }
  __syncthreads();
  if (t < 25) {
    int e = t / 5, f = t % 5;
    float acc = 0.f;
    if (which == 0) {
      #pragma unroll 8
      for (int d = 0; d < DD; ++d) acc += A[d*5+e] * Bsh[d*5+f];
      acc *= 0.125f * 1.44269504088896340736f;   // fold log2(e) for exp2
    } else {
      #pragma unroll 8
      for (int d = 0; d < DD; ++d) acc += A[d*5+e] * Bsh[f*64+d];
    }
    mp[which*960 + ((l*NH + h)*EDIM + e)*8 + f] = acc;
  }
}

// ---------------------------------------------------------------------------
// Kernel 2: one workgroup (128 thr = 2 waves) per batch element.
//   wave w owns HEAD-PAIR {2w, 2w+1}; lane i owns row i (slot A) and
//   row i+64 (slot B, rare).  Token state register-resident; o[j] fetched
//   with v_readlane (5 broadcasts amortized over 2 heads = 24 useful ops,
//   and 2 independent dot->exp->accum chains per lane for ILP).
//   Cross-wave traffic: each wave pre-normalizes + P-applies + SUMS its two
//   heads -> 5 floats per row; upd reads only the OTHER wave's entry (own
//   kept in registers).  Parity-dbuf'd -> ONE barrier per layer.
//   upd runs redundantly in both waves (bit-identical register copies).
//   Rep row (index nm): a=0 so exp2(0)=1 -> uniform weights; correction
//   w += (100-nm)*o_rep; inv = 1/100.
//   Layer constants (Wf,bf,g1,b1,g2,b2) cached in LDS at setup.
// ---------------------------------------------------------------------------
__global__ __launch_bounds__(BLK, 2) void encoder_kernel(
    const float* __restrict__ x,
    const float* __restrict__ mp,
    const float* __restrict__ Wf,
    const float* __restrict__ bfv,
    const float* __restrict__ g1,
    const float* __restrict__ b1,
    const float* __restrict__ g2,
    const float* __restrict__ b2,
    float* __restrict__ out)
{
  const int b = blockIdx.x, t = threadIdx.x;
  const int wv = t >> 6, ln = t & 63;     // wave = head-pair {2wv, 2wv+1}

  __shared__ float4 s_MP4[480];            // 7680 B : M then P
  __shared__ float4 s_wp4[2][2][104];      // 6656 B : [parity][wave][row] c[0..3]
  __shared__ float  s_wp1[2][2][104];      // 1664 B : c[4]
  __shared__ float4 s_i4[104];             // 1664 B : staging / final state
  __shared__ float  s_i1[104];             // 416 B
  __shared__ float  s_cf[152];             // Wf 0..74 | bf 75 | g1 90 | b1 105 | g2 120 | b2 135
  __shared__ int    s_cidx[NTOK];          // 400 B
  __shared__ unsigned long long s_bal[2];

  const float* mpf = (const float*)s_MP4;
  for (int r = t; r < 480; r += BLK) s_MP4[r] = ((const float4*)mp)[r];
  for (int r = t; r < 104; r += BLK) { s_i4[r] = make_float4(0.f,0.f,0.f,0.f); s_i1[r] = 0.f; }
  for (int r = t; r < 150; r += BLK) {
    float v;
    if      (r <  75) v = Wf[r];
    else if (r <  90) v = bfv[r-75];
    else if (r < 105) v = g1[r-90];
    else if (r < 120) v = b1[r-105];
    else if (r < 135) v = g2[r-120];
    else              v = b2[r-135];
    s_cf[r] = v;
  }

  // ---- setup: mask + ballot compaction into LDS staging ----
  float k0=0.f, k1=0.f, k2=0.f, msk=0.f;
  if (t < NTOK) {
    k0 = x[b*300 + 3*t];
    k1 = x[b*300 + 3*t + 1];
    k2 = x[b*300 + 3*t + 2];
    msk = (k2 > 0.f) ? 1.f : 0.f;
  }
  unsigned long long bal = __ballot(t < NTOK && msk != 0.f);
  if (t == 0)  s_bal[0] = bal;
  if (t == 64) s_bal[1] = bal;
  __syncthreads();
  const unsigned long long bw0 = s_bal[0], bw1 = s_bal[1];
  // readfirstlane: nm (and all derived bounds/indices) provably uniform
  const int nm = __builtin_amdgcn_readfirstlane(__popcll(bw0) + __popcll(bw1));
  if (t < NTOK) {
    int lane = t & 63;
    unsigned long long lm = (lane == 0) ? 0ull : ((1ull << lane) - 1ull);
    int pre = (t < 64) ? __popcll(bw0 & lm) : (__popcll(bw0) + __popcll(bw1 & lm));
    if (msk != 0.f) {
      s_i4[pre] = make_float4(k0, k1, k2, __sinf((float)t));
      s_i1[pre] = __cosf((float)t);
      s_cidx[t] = pre;
    } else {
      s_cidx[t] = nm;
    }
  }
  __syncthreads();

  const int rows = nm + 1;                  // includes rep token at index nm
  const bool twoRows = (rows > 64);
  const int jhiA = (nm < 64) ? nm : 64;     // slot-A keys (j < 64)
  const float wext = (float)(NTOK - nm);

  // ---- register-resident token state (identical in both waves) ----
  float oA0,oA1,oA2,oA3,oA4, oB0,oB1,oB2,oB3,oB4;
  { float4 v = s_i4[ln]; oA0=v.x; oA1=v.y; oA2=v.z; oA3=v.w; oA4=s_i1[ln]; }
  if (twoRows && ln < 40) {
    float4 v = s_i4[ln+64]; oB0=v.x; oB1=v.y; oB2=v.z; oB3=v.w; oB4=s_i1[ln+64];
  } else { oB0=0.f; oB1=0.f; oB2=0.f; oB3=0.f; oB4=0.f; }

  int bufp = 0;
  float cSA[5], cSB[5];                     // own-pair contribution, in regs

  for (int l = 0; l < NL; ++l) {
    const float* M0 = mpf + ((l*NH + 2*wv    )*EDIM)*8;
    const float* M1 = mpf + ((l*NH + 2*wv + 1)*EDIM)*8;
    const float* P0 = mpf + 960 + ((l*NH + 2*wv    )*EDIM)*8;
    const float* P1 = mpf + 960 + ((l*NH + 2*wv + 1)*EDIM)*8;

    // ---- attention + P-apply for one register-held row, BOTH heads ----
    auto attn_row = [&](float o0,float o1,float o2,float o3,float o4,
                        int row, float (&cS)[5]) {
      float oc[5] = {o0,o1,o2,o3,o4};
      float a00=0.f,a01=0.f,a02=0.f,a03=0.f,a04=0.f;
      float a10=0.f,a11=0.f,a12=0.f,a13=0.f,a14=0.f;
      #pragma unroll
      for (int e = 0; e < 5; ++e) {
        float4 m0 = *(const float4*)(M0 + e*8); float m04 = M0[e*8+4];
        float4 m1 = *(const float4*)(M1 + e*8); float m14 = M1[e*8+4];
        float v = oc[e];
        a00 += v*m0.x; a01 += v*m0.y; a02 += v*m0.z; a03 += v*m0.w; a04 += v*m04;
        a10 += v*m1.x; a11 += v*m1.y; a12 += v*m1.z; a13 += v*m1.w; a14 += v*m14;
      }
      const bool rep = (row == nm);
      if (rep) {
        a00=0.f;a01=0.f;a02=0.f;a03=0.f;a04=0.f;   // exp2(0)=1 -> uniform
        a10=0.f;a11=0.f;a12=0.f;a13=0.f;a14=0.f;
      }
      float ls0=0.f, ls1=0.f;
      float w00=0.f,w01=0.f,w02=0.f,w03=0.f,w04=0.f;
      float w10=0.f,w11=0.f,w12=0.f,w13=0.f,w14=0.f;
      #pragma unroll 4
      for (int j = 0; j < jhiA; ++j) {        // keys in slot A (j<64)
        float ox = RL(oA0,j), oy = RL(oA1,j), oz = RL(oA2,j),
              ow = RL(oA3,j), oe = RL(oA4,j);
        float s0 = (a00*ox + a01*oy) + ((a02*oz + a03*ow) + a04*oe);
        float s1 = (a10*ox + a11*oy) + ((a12*oz + a13*ow) + a14*oe);
        float p0 = fexp2(s0), p1 = fexp2(s1);   // 2 independent chains
        ls0 += p0; ls1 += p1;
        w00 += p0*ox; w01 += p0*oy; w02 += p0*oz; w03 += p0*ow; w04 += p0*oe;
        w10 += p1*ox; w11 += p1*oy; w12 += p1*oz; w13 += p1*ow; w14 += p1*oe;
      }
      if (twoRows) {
        #pragma unroll 4
        for (int j = 64; j < nm; ++j) {       // keys in slot B (j>=64)
          int jl = j - 64;
          float ox = RL(oB0,jl), oy = RL(oB1,jl), oz = RL(oB2,jl),
                ow = RL(oB3,jl), oe = RL(oB4,jl);
          float s0 = (a00*ox + a01*oy) + ((a02*oz + a03*ow) + a04*oe);
          float s1 = (a10*ox + a11*oy) + ((a12*oz + a13*ow) + a14*oe);
          float p0 = fexp2(s0), p1 = fexp2(s1);
          ls0 += p0; ls1 += p1;
          w00 += p0*ox; w01 += p0*oy; w02 += p0*oz; w03 += p0*ow; w04 += p0*oe;
          w10 += p1*ox; w11 += p1*oy; w12 += p1*oz; w13 += p1*ow; w14 += p1*oe;
        }
      }
      if (rep) {   // masked keys all carry the rep state
        w00 += wext*o0; w01 += wext*o1; w02 += wext*o2; w03 += wext*o3; w04 += wext*o4;
        w10 += wext*o0; w11 += wext*o1; w12 += wext*o2; w13 += wext*o3; w14 += wext*o4;
      }
      float inv0 = rep ? 0.01f : frcp(ls0);
      float inv1 = rep ? 0.01f : frcp(ls1);
      float wc0[5] = {w00*inv0, w01*inv0, w02*inv0, w03*inv0, w04*inv0};
      float wc1[5] = {w10*inv1, w11*inv1, w12*inv1, w13*inv1, w14*inv1};
      float c0=0.f,c1=0.f,c2=0.f,c3=0.f,c4=0.f;   // sum of BOTH heads @ P
      #pragma unroll
      for (int e = 0; e < 5; ++e) {
        float4 pr = *(const float4*)(P0 + e*8); float p4 = P0[e*8+4];
        c0 += wc0[e]*pr.x; c1 += wc0[e]*pr.y; c2 += wc0[e]*pr.z;
        c3 += wc0[e]*pr.w; c4 += wc0[e]*p4;
      }
      #pragma unroll
      for (int e = 0; e < 5; ++e) {
        float4 pr = *(const float4*)(P1 + e*8); float p4 = P1[e*8+4];
        c0 += wc1[e]*pr.x; c1 += wc1[e]*pr.y; c2 += wc1[e]*pr.z;
        c3 += wc1[e]*pr.w; c4 += wc1[e]*p4;
      }
      cS[0]=c0; cS[1]=c1; cS[2]=c2; cS[3]=c3; cS[4]=c4;
      s_wp4[bufp][wv][row] = make_float4(c0,c1,c2,c3);   // row<104 by guards
      s_wp1[bufp][wv][row] = c4;
    };

    attn_row(oA0,oA1,oA2,oA3,oA4, ln, cSA);
    if (twoRows && ln < 40) attn_row(oB0,oB1,oB2,oB3,oB4, ln+64, cSB);
    __syncthreads();   // the ONLY barrier per layer (wp parity dbuf)

    // ---- token update: redundant in both waves (regs stay coherent) ----
    auto upd = [&](float& p0,float& p1,float& p2,float& p3,float& p4,
                   float (&cS)[5], int row) {
      if (row >= rows) return;
      float4 wo = s_wp4[bufp][wv^1][row];     // other wave's head-pair
      float wo4 = s_wp1[bufp][wv^1][row];
      float y0 = p0 + cS[0] + wo.x,  y1 = p1 + cS[1] + wo.y;
      float y2 = p2 + cS[2] + wo.z,  y3 = p3 + cS[3] + wo.w;
      float y4 = p4 + cS[4] + wo4;
      float yv[5] = {y0,y1,y2,y3,y4};
      float mu = 0.2f*(y0+y1+y2+y3+y4);
      float var = 0.f;
      #pragma unroll
      for (int e = 0; e < 5; ++e) { float d = yv[e]-mu; var += d*d; }
      float iv = frsq(var*0.2f + 1e-5f);
      float l1[5];
      #pragma unroll
      for (int e = 0; e < 5; ++e)
        l1[e] = (yv[e]-mu)*iv*s_cf[90+l*5+e] + s_cf[105+l*5+e];
      float r2[5];
      #pragma unroll
      for (int e = 0; e < 5; ++e) {
        float acc = s_cf[75+l*5+e];
        #pragma unroll
        for (int f = 0; f < 5; ++f) acc += l1[f]*s_cf[l*25+e*5+f];
        acc = acc > 0.f ? acc : 0.f;
        r2[e] = acc + l1[e];
      }
      float mu2 = 0.2f*(r2[0]+r2[1]+r2[2]+r2[3]+r2[4]);
      float var2 = 0.f;
      #pragma unroll
      for (int e = 0; e < 5; ++e) { float d = r2[e]-mu2; var2 += d*d; }
      float iv2 = frsq(var2*0.2f + 1e-5f);
      p0 = (r2[0]-mu2)*iv2*s_cf[120+l*5+0] + s_cf[135+l*5+0];
      p1 = (r2[1]-mu2)*iv2*s_cf[120+l*5+1] + s_cf[135+l*5+1];
      p2 = (r2[2]-mu2)*iv2*s_cf[120+l*5+2] + s_cf[135+l*5+2];
      p3 = (r2[3]-mu2)*iv2*s_cf[120+l*5+3] + s_cf[135+l*5+3];
      p4 = (r2[4]-mu2)*iv2*s_cf[120+l*5+4] + s_cf[135+l*5+4];
    };
    upd(oA0,oA1,oA2,oA3,oA4, cSA, ln);
    if (twoRows && ln < 40) upd(oB0,oB1,oB2,oB3,oB4, cSB, ln+64);
    bufp ^= 1;
    // no trailing barrier: parity dbuf + next layer's pre-read barrier
  }

  // ---- writeback: wave 0's registers -> LDS, then expand to [N,E] ----
  if (wv == 0) {
    if (ln < rows) { s_i4[ln] = make_float4(oA0,oA1,oA2,oA3); s_i1[ln] = oA4; }
    if (twoRows && (ln + 64 < rows)) {
      s_i4[ln+64] = make_float4(oB0,oB1,oB2,oB3); s_i1[ln+64] = oB4;
    }
  }
  __syncthreads();
  for (int r = t; r < NTOK*EDIM; r += BLK) {
    int i = r / EDIM;
    int e = r - i*EDIM;
    int c = s_cidx[i];
    float v = (e < 4) ? ((const float*)&s_i4[c])[e] : s_i1[c];
    out[b*(NTOK*EDIM) + r] = v;
  }
}

extern "C" void kernel_launch(void* const* d_in, const int* in_sizes, int n_in,
                              void* d_out, int out_size, void* d_ws, size_t ws_size,
                              hipStream_t stream) {
  const float* x  = (const float*)d_in[0];
  const float* Wq = (const float*)d_in[1];
  const float* Wk = (const float*)d_in[2];
  const float* Wv = (const float*)d_in[3];
  const float* Wo = (const float*)d_in[4];
  const float* Wf = (const float*)d_in[5];
  const float* bf = (const float*)d_in[6];
  const float* g1 = (const float*)d_in[7];
  const float* b1 = (const float*)d_in[8];
  const float* g2 = (const float*)d_in[9];
  const float* b2 = (const float*)d_in[10];
  float* outp = (float*)d_out;
  float* mp   = (float*)d_ws;   // 1920 floats

  precompute_mp<<<24, 64, 0, stream>>>(Wq, Wk, Wv, Wo, mp);
  encoder_kernel<<<1024, BLK, 0, stream>>>(x, mp, Wf, bf, g1, b1, g2, b2, outp);
}